// Round 21
// baseline (759.413 us; speedup 1.0000x reference)
//
#include <hip/hip_runtime.h>

// ---------- types ----------
typedef __attribute__((ext_vector_type(8))) short bf16x8;
typedef __attribute__((ext_vector_type(8))) unsigned short u16x8;
typedef __attribute__((ext_vector_type(4))) float f32x4;

__device__ __forceinline__ unsigned short f2bf(float f) {
  union { float f; unsigned u; } v; v.f = f;
  unsigned r = v.u + 0x7FFFu + ((v.u >> 16) & 1u);
  return (unsigned short)(r >> 16);
}
__device__ __forceinline__ float max3f(float a, float b, float c) {
  float d;
  asm("v_max3_f32 %0, %1, %2, %3" : "=v"(d) : "v"(a), "v"(b), "v"(c));
  return d;
}
// compile-time float4-array word access (folds after unrolling)
__device__ __forceinline__ float cw(const float4 (&b)[14], int n) {
  float4 v = b[n >> 2];
  int c = n & 3;
  return c == 0 ? v.x : c == 1 ? v.y : c == 2 ? v.z : v.w;
}

// Problem: B=64 T=512 E=300 V=50000 H=2048 WP=2 OUT=5
// padded: EP=320, TP=516, KP=1600, M=32768
// Linearization: y(t) = c(t) + G(t)·prev(t),  c = b2 + W2^T relu(z),
// G = W2^T diag(1[z>0]) W1p.  CG[pos][n] (n<50: G[k][i], n=k*10+i;
// n=50..54: c_k without b2) = [mask|relu](z) @ Bmat^T, K=4096.

// ---------- kernel 1: prep — W1bT + gather + Bmat ----------
__global__ __launch_bounds__(256) void prep_kernel(
    const float* __restrict__ W1, unsigned short* __restrict__ W1bT,
    const int* __restrict__ idxs, const float* __restrict__ emb,
    unsigned short* __restrict__ P, const float* __restrict__ W2,
    unsigned short* __restrict__ Bmat) {
  const int bid = blockIdx.x;
  const int tid = threadIdx.x;
  if (bid < 800) {
    __shared__ float tile[64][65];
    int kb = bid % 25;
    int hb = bid / 25;
    int win = kb / 5;
    int e0 = (kb % 5) << 6;
    int hh = tid & 63;
    int kq = tid >> 6;
#pragma unroll
    for (int kk = kq; kk < 64; kk += 4) {
      int e = e0 + kk;
      float v = 0.f;
      if (e < 300) v = W1[(size_t)(win * 300 + e) * 2048 + hb * 64 + hh];
      tile[kk][hh] = v;
    }
    __syncthreads();
    int kk = tid & 63;
    int hq = tid >> 6;
#pragma unroll
    for (int h = hq; h < 64; h += 4) {
      W1bT[(size_t)(hb * 64 + h) * 1600 + kb * 64 + kk] = f2bf(tile[kk][h]);
    }
    return;
  }
  if (bid < 9056) {  // gather: 4 padded rows per block
    int g4 = (bid - 800) * 4;
#pragma unroll
    for (int r = 0; r < 4; ++r) {
      int g = g4 + r;  // b*516+tp
      int b = g / 516;
      int tp = g - b * 516;
      int tok = 0;
      if (tp >= 2 && tp < 514) tok = idxs[b * 512 + tp - 2];
      const float* erow = emb + (size_t)tok * 300;
      float v = (tid < 300) ? erow[tid] : 0.f;
      P[(size_t)g * 320 + tid] = f2bf(v);
      if (tid < 64) {
        int e = tid + 256;
        float v2 = (e < 300) ? erow[e] : 0.f;
        P[(size_t)g * 320 + e] = f2bf(v2);
      }
    }
    return;
  }
  // Bmat role: one n-row (0..63) per block.  Bmat[n][k], k<2048: h=k,
  // val = w2[h][kk]*w1p[ii][h] (n=kk*10+ii<50) else 0; k>=2048: h=k-2048,
  // val = w2[h][n-50] for n in 50..54 else 0.
  const int n = bid - 9056;
  const int kk = n / 10, ii = n - kk * 10;
  for (int k = tid; k < 4096; k += 256) {
    float val = 0.f;
    if (k < 2048) {
      if (n < 50)
        val = W2[k * 5 + kk] * W1[(size_t)(1500 + ii) * 2048 + k];
    } else {
      int h = k - 2048;
      if (n >= 50 && n < 55) val = W2[h * 5 + (n - 50)];
    }
    Bmat[(size_t)n * 4096 + k] = f2bf(val);
  }
}

// ---------- kernel 2: GEMM  Z = A @ W1bT + b1  (r20 body, unchanged) ----------
__global__ __launch_bounds__(256) void gemm_kernel(
    const unsigned short* __restrict__ P,
    const unsigned short* __restrict__ W1bT,
    const float* __restrict__ b1,
    unsigned short* __restrict__ Z) {
  __shared__ unsigned short smem[17408];
  unsigned short* As = smem;
  unsigned short* Bs = smem + 8192;
  const int tid = threadIdx.x;
  const int lane = tid & 63;
  const int w = tid >> 6;
  const int wm = w >> 1, wn = w & 1;
  const int lr = lane & 15;
  const int lk = (lane >> 4) << 3;

  const int bid = blockIdx.x;
  const int bswz = (bid & 7) * 512 + (bid >> 3);  // bijective XCD swizzle
  const int nt = bswz & 15;
  const int mt = bswz >> 4;
  const int b = mt >> 2;
  const int t0 = (mt & 3) << 7;

  const unsigned short* srcA[4];
  const unsigned short* srcB[4];
#pragma unroll
  for (int j = 0; j < 4; ++j) {
    int chunk = tid + j * 256;
    int row = chunk >> 3, kb = chunk & 7;
    int kbs = kb ^ (row & 7);
    srcA[j] = P + (size_t)(b * 516 + t0 + row) * 320 + (kbs << 3);
    srcB[j] = W1bT + (size_t)(nt * 128 + row) * 1600 + (kbs << 3);
  }

  f32x4 acc[4][4];
#pragma unroll
  for (int i = 0; i < 4; i++)
#pragma unroll
    for (int j = 0; j < 4; j++) acc[i][j] = (f32x4){0.f, 0.f, 0.f, 0.f};

  for (int kt = 0; kt < 25; ++kt) {
#pragma unroll
    for (int j = 0; j < 4; ++j) {
      int chunk = tid + j * 256;
      __builtin_amdgcn_global_load_lds(
          (const __attribute__((address_space(1))) unsigned int*)srcA[j],
          (__attribute__((address_space(3))) unsigned int*)&As[chunk << 3],
          16, 0, 0);
      srcA[j] += 64;
    }
#pragma unroll
    for (int j = 0; j < 4; ++j) {
      int chunk = tid + j * 256;
      __builtin_amdgcn_global_load_lds(
          (const __attribute__((address_space(1))) unsigned int*)srcB[j],
          (__attribute__((address_space(3))) unsigned int*)&Bs[chunk << 3],
          16, 0, 0);
      srcB[j] += 64;
    }
    __syncthreads();
#pragma unroll
    for (int ks = 0; ks < 64; ks += 32) {
      const int slot = (ks + lk) >> 3;
      bf16x8 af[4], bv[4];
#pragma unroll
      for (int am = 0; am < 4; ++am) {
        int row = (wm << 6) + (am << 4) + lr;
        af[am] = *(const bf16x8*)&As[(row << 6) + ((slot ^ (row & 7)) << 3)];
      }
#pragma unroll
      for (int bn = 0; bn < 4; ++bn) {
        int col = (wn << 6) + (bn << 4) + lr;
        bv[bn] = *(const bf16x8*)&Bs[(col << 6) + ((slot ^ (col & 7)) << 3)];
      }
#pragma unroll
      for (int am = 0; am < 4; ++am)
#pragma unroll
        for (int bn = 0; bn < 4; ++bn)
          acc[am][bn] = __builtin_amdgcn_mfma_f32_16x16x32_bf16(
              af[am], bv[bn], acc[am][bn], 0, 0, 0);
    }
    __syncthreads();
  }

  {
    const int rq = lane >> 4;
    const int rloc0 = (wm << 6) + (rq << 2);
    const int cloc0 = (wn << 6) + lr;
    float b1v[4];
#pragma unroll
    for (int bn = 0; bn < 4; ++bn)
      b1v[bn] = b1[nt * 128 + cloc0 + (bn << 4)];
#pragma unroll
    for (int am = 0; am < 4; ++am)
#pragma unroll
      for (int bn = 0; bn < 4; ++bn) {
        int rl = rloc0 + (am << 4);
        int cl = cloc0 + (bn << 4);
#pragma unroll
        for (int j = 0; j < 4; ++j)
          smem[(rl + j) * 136 + cl] = f2bf(acc[am][bn][j] + b1v[bn]);
      }
    __syncthreads();
    const int chunk = tid & 15;
    const int rsub = tid >> 4;
#pragma unroll
    for (int p = 0; p < 8; ++p) {
      int row = p * 16 + rsub;
      u16x8 v = *(const u16x8*)&smem[row * 136 + chunk * 8];
      *(u16x8*)&Z[(size_t)(mt * 128 + row) * 2048 + nt * 128 + chunk * 8] = v;
    }
  }
}

// ---------- kernel 3: linearize — CG[pos][64] = [mask|relu](Z) @ Bmat^T ----------
// M-tile 128, N=64 (single tile), K=4096 (64 steps).  A built in-register
// from Z (pure integer ops on bf16 raw), swizzled like gemm.
__global__ __launch_bounds__(256) void linearize_kernel(
    const unsigned short* __restrict__ Z,
    const unsigned short* __restrict__ Bmat,
    float* __restrict__ CG) {
  __shared__ unsigned short As[128 * 64];  // 16KB
  __shared__ unsigned short Bs[64 * 64];   // 8KB
  const int tid = threadIdx.x;
  const int lane = tid & 63;
  const int w = tid >> 6;  // wave -> 32-row M strip
  const int lr = lane & 15;
  const int lk = (lane >> 4) << 3;
  const int mt = blockIdx.x;  // 0..255

  f32x4 acc[2][4];
#pragma unroll
  for (int i = 0; i < 2; ++i)
#pragma unroll
    for (int j = 0; j < 4; ++j) acc[i][j] = (f32x4){0.f, 0.f, 0.f, 0.f};

  for (int kt = 0; kt < 64; ++kt) {
    const int ismask = (kt < 32);
    const int h0 = (ismask ? kt : kt - 32) << 6;
    // A: reg-stage Z (source-k pre-swizzled), convert to mask/relu, linear ds_write
#pragma unroll
    for (int j = 0; j < 4; ++j) {
      int chunk = tid + j * 256;  // 0..1023
      int row = chunk >> 3, kb = chunk & 7;
      int kbs = kb ^ (row & 7);
      u16x8 z8 = *(const u16x8*)&Z[(size_t)(mt * 128 + row) * 2048 + h0 +
                                   (kbs << 3)];
      u16x8 o;
#pragma unroll
      for (int e = 0; e < 8; ++e) {
        short zr = (short)z8[e];
        unsigned short v;
        if (ismask)
          v = (zr > 0) ? (unsigned short)0x3F80 : (unsigned short)0;  // 1.0 bf16
        else
          v = (zr > 0) ? (unsigned short)z8[e] : (unsigned short)0;   // relu
        o[e] = v;
      }
      *(u16x8*)&As[chunk << 3] = o;
    }
    // B: global_load_lds from Bmat[n][k]
#pragma unroll
    for (int j = 0; j < 2; ++j) {
      int chunk = tid + j * 256;  // 0..511
      int row = chunk >> 3, kb = chunk & 7;
      int kbs = kb ^ (row & 7);
      const unsigned short* src =
          Bmat + (size_t)row * 4096 + (kt << 6) + (kbs << 3);
      __builtin_amdgcn_global_load_lds(
          (const __attribute__((address_space(1))) unsigned int*)src,
          (__attribute__((address_space(3))) unsigned int*)&Bs[chunk << 3],
          16, 0, 0);
    }
    __syncthreads();
#pragma unroll
    for (int ks = 0; ks < 64; ks += 32) {
      const int slot = (ks + lk) >> 3;
      bf16x8 af[2], bv[4];
#pragma unroll
      for (int mf = 0; mf < 2; ++mf) {
        int row = (w << 5) + (mf << 4) + lr;
        af[mf] = *(const bf16x8*)&As[(row << 6) + ((slot ^ (row & 7)) << 3)];
      }
#pragma unroll
      for (int nf = 0; nf < 4; ++nf) {
        int col = (nf << 4) + lr;
        bv[nf] = *(const bf16x8*)&Bs[(col << 6) + ((slot ^ (col & 7)) << 3)];
      }
#pragma unroll
      for (int mf = 0; mf < 2; ++mf)
#pragma unroll
        for (int nf = 0; nf < 4; ++nf)
          acc[mf][nf] = __builtin_amdgcn_mfma_f32_16x16x32_bf16(
              af[mf], bv[nf], acc[mf][nf], 0, 0, 0);
    }
    __syncthreads();
  }
  // epilogue: direct fp32 stores (8.4MB total — small)
  const int rq = lane >> 4;
#pragma unroll
  for (int mf = 0; mf < 2; ++mf)
#pragma unroll
    for (int nf = 0; nf < 4; ++nf)
#pragma unroll
      for (int j = 0; j < 4; ++j) {
        int row = (w << 5) + (mf << 4) + (rq << 2) + j;
        int col = (nf << 4) + lr;
        CG[(size_t)(mt * 128 + row) * 64 + col] = acc[mf][nf][j];
      }
}

// ---------- kernel 4: scan-lite — single wave per batch, no barriers ----------
// y = c + b2 + G·prev ; p = softmax(y); prev = [prev[5:], p].
// 4-deep cyclic register buffers (static indexing), uniform broadcast loads.
#define LITE_BODY(BUF, T, PBUF, PT)                                          \
  do {                                                                       \
    float y0 = cw(BUF, 50) + b20, y1 = cw(BUF, 51) + b21,                    \
          y2 = cw(BUF, 52) + b22, y3 = cw(BUF, 53) + b23,                    \
          y4 = cw(BUF, 54) + b24;                                            \
    _Pragma("unroll") for (int i = 0; i < 10; ++i) {                         \
      y0 = fmaf(pr[i], cw(BUF, 0 + i), y0);                                  \
      y1 = fmaf(pr[i], cw(BUF, 10 + i), y1);                                 \
      y2 = fmaf(pr[i], cw(BUF, 20 + i), y2);                                 \
      y3 = fmaf(pr[i], cw(BUF, 30 + i), y3);                                 \
      y4 = fmaf(pr[i], cw(BUF, 40 + i), y4);                                 \
    }                                                                        \
    int ptc = (PT) < 511 ? (PT) : 511;                                       \
    _Pragma("unroll") for (int q = 0; q < 14; ++q) PBUF[q] =                 \
        *(const float4*)&CGb[(size_t)ptc * 64 + q * 4];                      \
    if (tid == 0) {                                                          \
      *(float4*)&out_lds[T][0] = (float4){y0, y1, y2, y3};                   \
      out_lds[T][4] = y4;                                                    \
    }                                                                        \
    float m = max3f(y0, y1, y2);                                             \
    m = max3f(m, y3, y4);                                                    \
    float mL = m * L2E;                                                      \
    float e0 = __builtin_amdgcn_exp2f(fmaf(y0, L2E, -mL));                   \
    float e1 = __builtin_amdgcn_exp2f(fmaf(y1, L2E, -mL));                   \
    float e2 = __builtin_amdgcn_exp2f(fmaf(y2, L2E, -mL));                   \
    float e3 = __builtin_amdgcn_exp2f(fmaf(y3, L2E, -mL));                   \
    float e4 = __builtin_amdgcn_exp2f(fmaf(y4, L2E, -mL));                   \
    float d = ((e0 + e1) + (e2 + e3)) + e4;                                  \
    float rf = __builtin_amdgcn_rcpf(d);                                     \
    pr[0] = pr[5]; pr[1] = pr[6]; pr[2] = pr[7]; pr[3] = pr[8];              \
    pr[4] = pr[9];                                                           \
    pr[5] = e0 * rf; pr[6] = e1 * rf; pr[7] = e2 * rf; pr[8] = e3 * rf;      \
    pr[9] = e4 * rf;                                                         \
  } while (0)

__global__ __launch_bounds__(64, 1) void scanlite_kernel(
    const float* __restrict__ CG, const float* __restrict__ b2,
    const float* __restrict__ istate, float* __restrict__ out) {
  const int b = blockIdx.x;
  const int tid = threadIdx.x;  // 0..63
  const float* CGb = CG + (size_t)b * 512 * 64;
  float* outb = out + (size_t)b * 512 * 5;
  __shared__ float out_lds[512][8];

  const float b20 = b2[0], b21 = b2[1], b22 = b2[2], b23 = b2[3],
              b24 = b2[4];
  const float L2E = 1.4426950408889634f;
  float pr[10];
#pragma unroll
  for (int i = 0; i < 10; ++i) pr[i] = istate[i];

  float4 bA[14], bB[14], bC[14], bD[14];
#pragma unroll
  for (int q = 0; q < 14; ++q) bA[q] = *(const float4*)&CGb[q * 4];
#pragma unroll
  for (int q = 0; q < 14; ++q) bB[q] = *(const float4*)&CGb[64 + q * 4];

  for (int t = 0; t < 512; t += 4) {
    LITE_BODY(bA, t + 0, bC, t + 2);
    LITE_BODY(bB, t + 1, bD, t + 3);
    LITE_BODY(bC, t + 2, bA, t + 4);
    LITE_BODY(bD, t + 3, bB, t + 5);
  }

  __syncthreads();
  float* dst = outb + tid * 40;  // thread owns steps 8*tid..8*tid+7
#pragma unroll
  for (int r = 0; r < 8; ++r) {
    int row = tid * 8 + r;
#pragma unroll
    for (int i = 0; i < 5; ++i) dst[r * 5 + i] = out_lds[row][i];
  }
}

// ---------- launcher ----------
extern "C" void kernel_launch(void* const* d_in, const int* in_sizes, int n_in,
                              void* d_out, int out_size, void* d_ws,
                              size_t ws_size, hipStream_t stream) {
  const int* idxs = (const int*)d_in[0];
  const float* emb = (const float*)d_in[1];
  const float* W1 = (const float*)d_in[2];
  const float* b1 = (const float*)d_in[3];
  const float* W2 = (const float*)d_in[4];
  const float* b2 = (const float*)d_in[5];
  const float* istate = (const float*)d_in[6];
  float* out = (float*)d_out;

  char* ws = (char*)d_ws;
  unsigned short* P = (unsigned short*)ws;                           // 21,135,360
  unsigned short* W1bT = (unsigned short*)(ws + 21135360);           //  6,553,600
  unsigned short* Z = (unsigned short*)(ws + 27688960);              // 134,217,728
  unsigned short* Bmat = (unsigned short*)(ws + 161906688);          //    524,288
  float* CG = (float*)ws;  // aliases P (dead after gemm); 8,388,608 B

  hipLaunchKernelGGL(prep_kernel, dim3(800 + 8256 + 64), dim3(256), 0, stream,
                     W1, W1bT, idxs, emb, P, W2, Bmat);
  hipLaunchKernelGGL(gemm_kernel, dim3(4096), dim3(256), 0, stream, P, W1bT,
                     b1, Z);
  hipLaunchKernelGGL(linearize_kernel, dim3(256), dim3(256), 0, stream, Z,
                     Bmat, CG);
  hipLaunchKernelGGL(scanlite_kernel, dim3(64), dim3(64), 0, stream, CG, b2,
                     istate, out);
}

// Round 22
// 429.054 us; speedup vs baseline: 1.7700x; 1.7700x over previous
//
#include <hip/hip_runtime.h>

// ---------- types ----------
typedef __attribute__((ext_vector_type(8))) short bf16x8;
typedef __attribute__((ext_vector_type(8))) unsigned short u16x8;
typedef __attribute__((ext_vector_type(4))) float f32x4;

__device__ __forceinline__ unsigned short f2bf(float f) {
  union { float f; unsigned u; } v; v.f = f;
  unsigned r = v.u + 0x7FFFu + ((v.u >> 16) & 1u);
  return (unsigned short)(r >> 16);
}
__device__ __forceinline__ float max3f(float a, float b, float c) {
  float d;
  asm("v_max3_f32 %0, %1, %2, %3" : "=v"(d) : "v"(a), "v"(b), "v"(c));
  return d;
}
// compile-time float4-array word access (folds after unrolling)
__device__ __forceinline__ float cw(const float4 (&b)[14], int n) {
  float4 v = b[n >> 2];
  int c = n & 3;
  return c == 0 ? v.x : c == 1 ? v.y : c == 2 ? v.z : v.w;
}

// Problem: B=64 T=512 E=300 V=50000 H=2048 WP=2 OUT=5
// padded: EP=320, TP=516, KP=1600, M=32768
// Linearization: y(t) = c(t) + G(t)·prev(t),  c = b2 + W2^T relu(z),
// G = W2^T diag(1[z>0]) W1p.  CG[pos][n] (n<50: G[k][i], n=k*10+i;
// n=50..54: c_k w/o b2) = mask(z)@Bm^T + relu(z)@Br^T, K=2048 each.

// ---------- kernel 1: prep — W1bT + gather + Bmat ----------
__global__ __launch_bounds__(256) void prep_kernel(
    const float* __restrict__ W1, unsigned short* __restrict__ W1bT,
    const int* __restrict__ idxs, const float* __restrict__ emb,
    unsigned short* __restrict__ P, const float* __restrict__ W2,
    unsigned short* __restrict__ Bmat) {
  const int bid = blockIdx.x;
  const int tid = threadIdx.x;
  if (bid < 800) {
    __shared__ float tile[64][65];
    int kb = bid % 25;
    int hb = bid / 25;
    int win = kb / 5;
    int e0 = (kb % 5) << 6;
    int hh = tid & 63;
    int kq = tid >> 6;
#pragma unroll
    for (int kk = kq; kk < 64; kk += 4) {
      int e = e0 + kk;
      float v = 0.f;
      if (e < 300) v = W1[(size_t)(win * 300 + e) * 2048 + hb * 64 + hh];
      tile[kk][hh] = v;
    }
    __syncthreads();
    int kk = tid & 63;
    int hq = tid >> 6;
#pragma unroll
    for (int h = hq; h < 64; h += 4) {
      W1bT[(size_t)(hb * 64 + h) * 1600 + kb * 64 + kk] = f2bf(tile[kk][h]);
    }
    return;
  }
  if (bid < 9056) {  // gather: 4 padded rows per block
    int g4 = (bid - 800) * 4;
#pragma unroll
    for (int r = 0; r < 4; ++r) {
      int g = g4 + r;  // b*516+tp
      int b = g / 516;
      int tp = g - b * 516;
      int tok = 0;
      if (tp >= 2 && tp < 514) tok = idxs[b * 512 + tp - 2];
      const float* erow = emb + (size_t)tok * 300;
      float v = (tid < 300) ? erow[tid] : 0.f;
      P[(size_t)g * 320 + tid] = f2bf(v);
      if (tid < 64) {
        int e = tid + 256;
        float v2 = (e < 300) ? erow[e] : 0.f;
        P[(size_t)g * 320 + e] = f2bf(v2);
      }
    }
    return;
  }
  // Bmat: one n-row (0..63) per block.  k<2048: mask part Bm[n][k] =
  // w2[k][kk]*w1p[ii][k] (n=kk*10+ii<50); k>=2048: relu part Br[n][k-2048] =
  // w2[h][n-50] for n=50..54.
  const int n = bid - 9056;
  const int kk = n / 10, ii = n - kk * 10;
  for (int k = tid; k < 4096; k += 256) {
    float val = 0.f;
    if (k < 2048) {
      if (n < 50)
        val = W2[k * 5 + kk] * W1[(size_t)(1500 + ii) * 2048 + k];
    } else {
      int h = k - 2048;
      if (n >= 50 && n < 55) val = W2[h * 5 + (n - 50)];
    }
    Bmat[(size_t)n * 4096 + k] = f2bf(val);
  }
}

// ---------- kernel 2: GEMM  Z = A @ W1bT + b1  (r20 body, unchanged) ----------
__global__ __launch_bounds__(256) void gemm_kernel(
    const unsigned short* __restrict__ P,
    const unsigned short* __restrict__ W1bT,
    const float* __restrict__ b1,
    unsigned short* __restrict__ Z) {
  __shared__ unsigned short smem[17408];
  unsigned short* As = smem;
  unsigned short* Bs = smem + 8192;
  const int tid = threadIdx.x;
  const int lane = tid & 63;
  const int w = tid >> 6;
  const int wm = w >> 1, wn = w & 1;
  const int lr = lane & 15;
  const int lk = (lane >> 4) << 3;

  const int bid = blockIdx.x;
  const int bswz = (bid & 7) * 512 + (bid >> 3);  // bijective XCD swizzle
  const int nt = bswz & 15;
  const int mt = bswz >> 4;
  const int b = mt >> 2;
  const int t0 = (mt & 3) << 7;

  const unsigned short* srcA[4];
  const unsigned short* srcB[4];
#pragma unroll
  for (int j = 0; j < 4; ++j) {
    int chunk = tid + j * 256;
    int row = chunk >> 3, kb = chunk & 7;
    int kbs = kb ^ (row & 7);
    srcA[j] = P + (size_t)(b * 516 + t0 + row) * 320 + (kbs << 3);
    srcB[j] = W1bT + (size_t)(nt * 128 + row) * 1600 + (kbs << 3);
  }

  f32x4 acc[4][4];
#pragma unroll
  for (int i = 0; i < 4; i++)
#pragma unroll
    for (int j = 0; j < 4; j++) acc[i][j] = (f32x4){0.f, 0.f, 0.f, 0.f};

  for (int kt = 0; kt < 25; ++kt) {
#pragma unroll
    for (int j = 0; j < 4; ++j) {
      int chunk = tid + j * 256;
      __builtin_amdgcn_global_load_lds(
          (const __attribute__((address_space(1))) unsigned int*)srcA[j],
          (__attribute__((address_space(3))) unsigned int*)&As[chunk << 3],
          16, 0, 0);
      srcA[j] += 64;
    }
#pragma unroll
    for (int j = 0; j < 4; ++j) {
      int chunk = tid + j * 256;
      __builtin_amdgcn_global_load_lds(
          (const __attribute__((address_space(1))) unsigned int*)srcB[j],
          (__attribute__((address_space(3))) unsigned int*)&Bs[chunk << 3],
          16, 0, 0);
      srcB[j] += 64;
    }
    __syncthreads();
#pragma unroll
    for (int ks = 0; ks < 64; ks += 32) {
      const int slot = (ks + lk) >> 3;
      bf16x8 af[4], bv[4];
#pragma unroll
      for (int am = 0; am < 4; ++am) {
        int row = (wm << 6) + (am << 4) + lr;
        af[am] = *(const bf16x8*)&As[(row << 6) + ((slot ^ (row & 7)) << 3)];
      }
#pragma unroll
      for (int bn = 0; bn < 4; ++bn) {
        int col = (wn << 6) + (bn << 4) + lr;
        bv[bn] = *(const bf16x8*)&Bs[(col << 6) + ((slot ^ (col & 7)) << 3)];
      }
#pragma unroll
      for (int am = 0; am < 4; ++am)
#pragma unroll
        for (int bn = 0; bn < 4; ++bn)
          acc[am][bn] = __builtin_amdgcn_mfma_f32_16x16x32_bf16(
              af[am], bv[bn], acc[am][bn], 0, 0, 0);
    }
    __syncthreads();
  }

  {
    const int rq = lane >> 4;
    const int rloc0 = (wm << 6) + (rq << 2);
    const int cloc0 = (wn << 6) + lr;
    float b1v[4];
#pragma unroll
    for (int bn = 0; bn < 4; ++bn)
      b1v[bn] = b1[nt * 128 + cloc0 + (bn << 4)];
#pragma unroll
    for (int am = 0; am < 4; ++am)
#pragma unroll
      for (int bn = 0; bn < 4; ++bn) {
        int rl = rloc0 + (am << 4);
        int cl = cloc0 + (bn << 4);
#pragma unroll
        for (int j = 0; j < 4; ++j)
          smem[(rl + j) * 136 + cl] = f2bf(acc[am][bn][j] + b1v[bn]);
      }
    __syncthreads();
    const int chunk = tid & 15;
    const int rsub = tid >> 4;
#pragma unroll
    for (int p = 0; p < 8; ++p) {
      int row = p * 16 + rsub;
      u16x8 v = *(const u16x8*)&smem[row * 136 + chunk * 8];
      *(u16x8*)&Z[(size_t)(mt * 128 + row) * 2048 + nt * 128 + chunk * 8] = v;
    }
  }
}

// ---------- kernel 3: linearize — CG = mask(Z)@Bm^T + relu(Z)@Br^T ----------
// r21 fix: mask/relu interleaved per kt (one Z read builds BOTH A tiles;
// both accumulate into the same acc), zreg prefetch for kt+1 stays in
// flight across raw counted barriers.  32 kt iterations, K=2048 each side.
__global__ __launch_bounds__(256) void linearize_kernel(
    const unsigned short* __restrict__ Z,
    const unsigned short* __restrict__ Bmat,
    float* __restrict__ CG) {
  __shared__ unsigned short Am[128 * 64];  // 16KB mask tile
  __shared__ unsigned short Ar[128 * 64];  // 16KB relu tile
  __shared__ unsigned short Bm[64 * 64];   // 8KB
  __shared__ unsigned short Br[64 * 64];   // 8KB
  const int tid = threadIdx.x;
  const int lane = tid & 63;
  const int w = tid >> 6;  // wave -> 32-row M strip
  const int lr = lane & 15;
  const int lk = (lane >> 4) << 3;
  const int mt = blockIdx.x;  // 0..255

  // per-thread Z source coords (swizzled k-slot)
  int rowZ[4], kbsZ[4];
#pragma unroll
  for (int j = 0; j < 4; ++j) {
    int chunk = tid + j * 256;
    rowZ[j] = chunk >> 3;
    kbsZ[j] = (chunk & 7) ^ (rowZ[j] & 7);
  }

  f32x4 acc[2][4];
#pragma unroll
  for (int i = 0; i < 2; ++i)
#pragma unroll
    for (int j = 0; j < 4; ++j) acc[i][j] = (f32x4){0.f, 0.f, 0.f, 0.f};

  const bf16x8 C1 = (bf16x8){0x3F80, 0x3F80, 0x3F80, 0x3F80,
                             0x3F80, 0x3F80, 0x3F80, 0x3F80};
  bf16x8 zcur[4], znxt[4];
#pragma unroll
  for (int j = 0; j < 4; ++j)
    zcur[j] = *(const bf16x8*)&Z[(size_t)(mt * 128 + rowZ[j]) * 2048 +
                                 (kbsZ[j] << 3)];

  for (int kt = 0; kt < 32; ++kt) {
    // convert zcur -> both A tiles (packed i16 sign trick), linear ds_write
#pragma unroll
    for (int j = 0; j < 4; ++j) {
      int chunk = tid + j * 256;
      bf16x8 s = zcur[j] >> 15;   // arith: 0xFFFF neg, 0 pos/zero
      bf16x8 notm = ~s;
      bf16x8 m8 = notm & C1;
      bf16x8 r8 = notm & zcur[j];
      *(bf16x8*)&Am[chunk << 3] = m8;
      *(bf16x8*)&Ar[chunk << 3] = r8;
    }
    // B tiles for this kt (mask half k<2048, relu half k>=2048)
#pragma unroll
    for (int j = 0; j < 2; ++j) {
      int chunk = tid + j * 256;
      int row = chunk >> 3, kb = chunk & 7;
      int kbs = kb ^ (row & 7);
      const unsigned short* sm =
          Bmat + (size_t)row * 4096 + (kt << 6) + (kbs << 3);
      __builtin_amdgcn_global_load_lds(
          (const __attribute__((address_space(1))) unsigned int*)sm,
          (__attribute__((address_space(3))) unsigned int*)&Bm[chunk << 3],
          16, 0, 0);
      const unsigned short* sr =
          Bmat + (size_t)row * 4096 + 2048 + (kt << 6) + (kbs << 3);
      __builtin_amdgcn_global_load_lds(
          (const __attribute__((address_space(1))) unsigned int*)sr,
          (__attribute__((address_space(3))) unsigned int*)&Br[chunk << 3],
          16, 0, 0);
    }
    __builtin_amdgcn_sched_barrier(0);
    // zreg prefetch for kt+1 (after B issues; stays in flight across barrier)
    {
      int ktn = (kt + 1 < 32) ? kt + 1 : 31;
#pragma unroll
      for (int j = 0; j < 4; ++j)
        znxt[j] = *(const bf16x8*)&Z[(size_t)(mt * 128 + rowZ[j]) * 2048 +
                                     (ktn << 6) + (kbsZ[j] << 3)];
    }
    __builtin_amdgcn_sched_barrier(0);
    asm volatile("s_waitcnt lgkmcnt(0) vmcnt(4)" ::: "memory");
    __builtin_amdgcn_sched_barrier(0);
    __builtin_amdgcn_s_barrier();
    __builtin_amdgcn_sched_barrier(0);

#pragma unroll
    for (int ks = 0; ks < 64; ks += 32) {
      const int slot = (ks + lk) >> 3;
      bf16x8 afm[2], afr[2], bvm[4], bvr[4];
#pragma unroll
      for (int mf = 0; mf < 2; ++mf) {
        int row = (w << 5) + (mf << 4) + lr;
        int off = (row << 6) + ((slot ^ (row & 7)) << 3);
        afm[mf] = *(const bf16x8*)&Am[off];
        afr[mf] = *(const bf16x8*)&Ar[off];
      }
#pragma unroll
      for (int nf = 0; nf < 4; ++nf) {
        int col = (nf << 4) + lr;
        int off = (col << 6) + ((slot ^ (col & 7)) << 3);
        bvm[nf] = *(const bf16x8*)&Bm[off];
        bvr[nf] = *(const bf16x8*)&Br[off];
      }
#pragma unroll
      for (int mf = 0; mf < 2; ++mf)
#pragma unroll
        for (int nf = 0; nf < 4; ++nf) {
          acc[mf][nf] = __builtin_amdgcn_mfma_f32_16x16x32_bf16(
              afm[mf], bvm[nf], acc[mf][nf], 0, 0, 0);
          acc[mf][nf] = __builtin_amdgcn_mfma_f32_16x16x32_bf16(
              afr[mf], bvr[nf], acc[mf][nf], 0, 0, 0);
        }
    }
    asm volatile("s_waitcnt lgkmcnt(0)" ::: "memory");
    __builtin_amdgcn_sched_barrier(0);
    __builtin_amdgcn_s_barrier();
    __builtin_amdgcn_sched_barrier(0);
#pragma unroll
    for (int j = 0; j < 4; ++j) zcur[j] = znxt[j];
  }
  // epilogue: direct fp32 stores (8.4MB total)
  const int rq = lane >> 4;
#pragma unroll
  for (int mf = 0; mf < 2; ++mf)
#pragma unroll
    for (int nf = 0; nf < 4; ++nf)
#pragma unroll
      for (int j = 0; j < 4; ++j) {
        int row = (w << 5) + (mf << 4) + (rq << 2) + j;
        int col = (nf << 4) + lr;
        CG[(size_t)(mt * 128 + row) * 64 + col] = acc[mf][nf][j];
      }
}

// ---------- kernel 4: scan-lite — 1 wave/batch, LDS chunk pipeline ----------
// CG rows stream through a 2×(64-row) LDS double buffer via global_load_lds
// (counted vmcnt gates at t%64==0 issue / t%64==56 wait — 56 steps of
// latency cover).  In-loop reads are uniform ds_read broadcasts.
#define LITE_BODY(BUF, T, PBUF, PT)                                          \
  do {                                                                       \
    float y0 = cw(BUF, 50) + b20, y1 = cw(BUF, 51) + b21,                    \
          y2 = cw(BUF, 52) + b22, y3 = cw(BUF, 53) + b23,                    \
          y4 = cw(BUF, 54) + b24;                                            \
    _Pragma("unroll") for (int i = 0; i < 10; ++i) {                         \
      y0 = fmaf(pr[i], cw(BUF, 0 + i), y0);                                  \
      y1 = fmaf(pr[i], cw(BUF, 10 + i), y1);                                 \
      y2 = fmaf(pr[i], cw(BUF, 20 + i), y2);                                 \
      y3 = fmaf(pr[i], cw(BUF, 30 + i), y3);                                 \
      y4 = fmaf(pr[i], cw(BUF, 40 + i), y4);                                 \
    }                                                                        \
    int ptc = (PT) < 511 ? (PT) : 511;                                       \
    const float* ls_ = &lds_cg[(ptc & 127) << 6];                            \
    _Pragma("unroll") for (int q = 0; q < 14; ++q) PBUF[q] =                 \
        *(const float4*)&ls_[q * 4];                                         \
    if (tid == 0) {                                                          \
      *(float4*)&out_lds[T][0] = (float4){y0, y1, y2, y3};                   \
      out_lds[T][4] = y4;                                                    \
    }                                                                        \
    float m = max3f(y0, y1, y2);                                             \
    m = max3f(m, y3, y4);                                                    \
    float mL = m * L2E;                                                      \
    float e0 = __builtin_amdgcn_exp2f(fmaf(y0, L2E, -mL));                   \
    float e1 = __builtin_amdgcn_exp2f(fmaf(y1, L2E, -mL));                   \
    float e2 = __builtin_amdgcn_exp2f(fmaf(y2, L2E, -mL));                   \
    float e3 = __builtin_amdgcn_exp2f(fmaf(y3, L2E, -mL));                   \
    float e4 = __builtin_amdgcn_exp2f(fmaf(y4, L2E, -mL));                   \
    float d = ((e0 + e1) + (e2 + e3)) + e4;                                  \
    float rf = __builtin_amdgcn_rcpf(d);                                     \
    pr[0] = pr[5]; pr[1] = pr[6]; pr[2] = pr[7]; pr[3] = pr[8];              \
    pr[4] = pr[9];                                                           \
    pr[5] = e0 * rf; pr[6] = e1 * rf; pr[7] = e2 * rf; pr[8] = e3 * rf;      \
    pr[9] = e4 * rf;                                                         \
  } while (0)

__global__ __launch_bounds__(64, 1) void scanlite_kernel(
    const float* __restrict__ CG, const float* __restrict__ b2,
    const float* __restrict__ istate, float* __restrict__ out) {
  const int b = blockIdx.x;
  const int tid = threadIdx.x;  // 0..63
  const float* CGb = CG + (size_t)b * 512 * 64;
  float* outb = out + (size_t)b * 512 * 5;
  __shared__ float lds_cg[2 * 64 * 64];  // 32KB double buffer
  __shared__ float out_lds[512][8];      // 16KB

  const float b20 = b2[0], b21 = b2[1], b22 = b2[2], b23 = b2[3],
              b24 = b2[4];
  const float L2E = 1.4426950408889634f;
  float pr[10];
#pragma unroll
  for (int i = 0; i < 10; ++i) pr[i] = istate[i];

  // stage chunk c (64 rows = 16KB): 16 gload_lds of 16B per thread
#define STAGE_CHUNK(c)                                                       \
  do {                                                                       \
    _Pragma("unroll") for (int i = 0; i < 16; ++i) {                         \
      const float* src = CGb + (size_t)(c) * 4096 + i * 256 + tid * 4;       \
      __builtin_amdgcn_global_load_lds(                                      \
          (const __attribute__((address_space(1))) unsigned int*)src,        \
          (__attribute__((address_space(3))) unsigned int*)                  \
              ((char*)lds_cg + ((c) & 1) * 16384 + i * 1024 + tid * 16),     \
          16, 0, 0);                                                         \
    }                                                                        \
  } while (0)

  STAGE_CHUNK(0);
  STAGE_CHUNK(1);
  asm volatile("s_waitcnt vmcnt(16)" ::: "memory");  // chunk 0 resident
  __builtin_amdgcn_sched_barrier(0);

  float4 bA[14], bB[14], bC[14], bD[14];
#pragma unroll
  for (int q = 0; q < 14; ++q) bA[q] = *(const float4*)&lds_cg[q * 4];
#pragma unroll
  for (int q = 0; q < 14; ++q) bB[q] = *(const float4*)&lds_cg[64 + q * 4];

  for (int t = 0; t < 512; t += 4) {
    if ((t & 63) == 0 && t > 0) {
      int nc = (t >> 6) + 1;
      if (nc < 8) STAGE_CHUNK(nc);
    }
    if ((t & 63) == 56) {  // ensure next chunk resident before cross-reads
      asm volatile("s_waitcnt vmcnt(0)" ::: "memory");
      __builtin_amdgcn_sched_barrier(0);
    }
    LITE_BODY(bA, t + 0, bC, t + 2);
    LITE_BODY(bB, t + 1, bD, t + 3);
    LITE_BODY(bC, t + 2, bA, t + 4);
    LITE_BODY(bD, t + 3, bB, t + 5);
  }

  __builtin_amdgcn_s_barrier();
  float* dst = outb + tid * 40;  // thread owns steps 8*tid..8*tid+7
#pragma unroll
  for (int r = 0; r < 8; ++r) {
    int row = tid * 8 + r;
#pragma unroll
    for (int i = 0; i < 5; ++i) dst[r * 5 + i] = out_lds[row][i];
  }
#undef STAGE_CHUNK
}

// ---------- launcher ----------
extern "C" void kernel_launch(void* const* d_in, const int* in_sizes, int n_in,
                              void* d_out, int out_size, void* d_ws,
                              size_t ws_size, hipStream_t stream) {
  const int* idxs = (const int*)d_in[0];
  const float* emb = (const float*)d_in[1];
  const float* W1 = (const float*)d_in[2];
  const float* b1 = (const float*)d_in[3];
  const float* W2 = (const float*)d_in[4];
  const float* b2 = (const float*)d_in[5];
  const float* istate = (const float*)d_in[6];
  float* out = (float*)d_out;

  char* ws = (char*)d_ws;
  unsigned short* P = (unsigned short*)ws;                           // 21,135,360
  unsigned short* W1bT = (unsigned short*)(ws + 21135360);           //  6,553,600
  unsigned short* Z = (unsigned short*)(ws + 27688960);              // 134,217,728
  unsigned short* Bmat = (unsigned short*)(ws + 161906688);          //    524,288
  float* CG = (float*)ws;  // aliases P (dead after gemm); 8,388,608 B

  hipLaunchKernelGGL(prep_kernel, dim3(800 + 8256 + 64), dim3(256), 0, stream,
                     W1, W1bT, idxs, emb, P, W2, Bmat);
  hipLaunchKernelGGL(gemm_kernel, dim3(4096), dim3(256), 0, stream, P, W1bT,
                     b1, Z);
  hipLaunchKernelGGL(linearize_kernel, dim3(256), dim3(256), 0, stream, Z,
                     Bmat, CG);
  hipLaunchKernelGGL(scanlite_kernel, dim3(64), dim3(64), 0, stream, CG, b2,
                     istate, out);
}